// Round 1
// baseline (1698.169 us; speedup 1.0000x reference)
//
#include <hip/hip_runtime.h>

// CausaFormer forward on MI355X. fp16 MFMA GEMMs w/ fp32 accumulate.
// B=2, L=1024, D=1024, NL=6, H=16, DK=64.

typedef _Float16 f16;
typedef _Float16 f16x8 __attribute__((ext_vector_type(8)));
typedef _Float16 f16x4v __attribute__((ext_vector_type(4)));
typedef float f32x4 __attribute__((ext_vector_type(4)));

static_assert(sizeof(f16) == 2, "f16 size");

#define LQ 1024
#define DQ 1024
#define HQ 16
#define DKQ 64

// Epilogue modes
enum {
  EPI_F16 = 0,   // f16 store, no bias           (cm@x, PV)
  EPI_F16B,      // f16 store + bias             (embedding)
  EPI_SIG,       // sigmoid(v+bias) -> f16       (causal-graph gate)
  EPI_RELU,      // relu(v+bias) -> f16          (fc1)
  EPI_QKV,       // v+bias -> f16 at [B,H,L,DK]  (q,k proj)
  EPI_VT,        // v+bias -> f16 at [B,H,DK,L]  (v proj, pre-transposed)
  EPI_RESID,     // v+bias -> f32 C and f16 C2   (wo: residual + fc1 input)
  EPI_FC2,       // v+bias+resid -> f32          (fc2: pre-LN sum)
  EPI_SCORES,    // v*0.125 -> f32               (QK^T)
  EPI_OUT        // v+bias -> f32                (final projection)
};

struct GP {
  const f16* A; const f16* W; const float* bias;
  void* C; void* C2; const float* resid;
  int K; int lda; int ldw; int ldc;
  long long sA; long long sW; long long sC;
};

// NT GEMM: C[m][n] = epi( sum_k A[m][k] * W[n][k] ).
// 256 threads = 4 waves in 2x2 grid. BK=32 (one mfma_16x16x32 K-step).
// Double-buffered LDS, reg-staged global->LDS, +8 f16 row pad (2-way max conflicts).
template<int BM, int BN, int EPI>
__global__ __launch_bounds__(256, 2) void gemm_nt(GP p) {
  constexpr int BK = 32;
  constexpr int LRS = 40;          // f16 row stride in LDS (80B, 16B-aligned, bank-spread)
  constexpr int FM = BM / 32;      // 16x16 frags per wave along M
  constexpr int FN = BN / 32;      // frags along N
  constexpr int APASS = BM / 64;   // 256-slot staging passes (slot = 16B)
  constexpr int BPASS = BN / 64;

  __shared__ f16 As[2][BM * LRS];
  __shared__ f16 Bs[2][BN * LRS];

  const int tid = threadIdx.x;
  const int lane = tid & 63;
  const int wid = tid >> 6;
  const int wr = wid >> 1;
  const int wc = wid & 1;
  const int z = blockIdx.z;
  const int m0 = blockIdx.y * BM;
  const int n0 = blockIdx.x * BN;

  const f16* Ab = p.A + (long long)z * p.sA;
  const f16* Wb = p.W + (long long)z * p.sW;

  f16x8 ra[APASS], rb[BPASS];

  // ---- stage tile 0 ----
#pragma unroll
  for (int u = 0; u < APASS; ++u) {
    int s = u * 256 + tid; int row = s >> 2, sl = s & 3;
    ra[u] = *(const f16x8*)(Ab + (long long)(m0 + row) * p.lda + sl * 8);
  }
#pragma unroll
  for (int u = 0; u < BPASS; ++u) {
    int s = u * 256 + tid; int row = s >> 2, sl = s & 3;
    rb[u] = *(const f16x8*)(Wb + (long long)(n0 + row) * p.ldw + sl * 8);
  }
#pragma unroll
  for (int u = 0; u < APASS; ++u) {
    int s = u * 256 + tid;
    *(f16x8*)(&As[0][(s >> 2) * LRS + (s & 3) * 8]) = ra[u];
  }
#pragma unroll
  for (int u = 0; u < BPASS; ++u) {
    int s = u * 256 + tid;
    *(f16x8*)(&Bs[0][(s >> 2) * LRS + (s & 3) * 8]) = rb[u];
  }
  __syncthreads();

  f32x4 acc[FM][FN] = {};

  const int nt = p.K / BK;
  int cur = 0;
  for (int t = 0; t < nt; ++t) {
    if (t + 1 < nt) {
      const int ko = (t + 1) * BK;
#pragma unroll
      for (int u = 0; u < APASS; ++u) {
        int s = u * 256 + tid; int row = s >> 2, sl = s & 3;
        ra[u] = *(const f16x8*)(Ab + (long long)(m0 + row) * p.lda + ko + sl * 8);
      }
#pragma unroll
      for (int u = 0; u < BPASS; ++u) {
        int s = u * 256 + tid; int row = s >> 2, sl = s & 3;
        rb[u] = *(const f16x8*)(Wb + (long long)(n0 + row) * p.ldw + ko + sl * 8);
      }
    }
    {
      const int kc = (lane >> 4) * 8;   // k chunk within BK=32
      const int lr = lane & 15;         // A-row / B-col within frag
      f16x8 fa[FM], fb[FN];
#pragma unroll
      for (int i = 0; i < FM; ++i)
        fa[i] = *(const f16x8*)(&As[cur][(wr * FM * 16 + i * 16 + lr) * LRS + kc]);
#pragma unroll
      for (int j = 0; j < FN; ++j)
        fb[j] = *(const f16x8*)(&Bs[cur][(wc * FN * 16 + j * 16 + lr) * LRS + kc]);
#pragma unroll
      for (int i = 0; i < FM; ++i)
#pragma unroll
        for (int j = 0; j < FN; ++j)
          acc[i][j] = __builtin_amdgcn_mfma_f32_16x16x32_f16(fa[i], fb[j], acc[i][j], 0, 0, 0);
    }
    if (t + 1 < nt) {
#pragma unroll
      for (int u = 0; u < APASS; ++u) {
        int s = u * 256 + tid;
        *(f16x8*)(&As[cur ^ 1][(s >> 2) * LRS + (s & 3) * 8]) = ra[u];
      }
#pragma unroll
      for (int u = 0; u < BPASS; ++u) {
        int s = u * 256 + tid;
        *(f16x8*)(&Bs[cur ^ 1][(s >> 2) * LRS + (s & 3) * 8]) = rb[u];
      }
    }
    __syncthreads();
    cur ^= 1;
  }

  // ---- epilogue: D[row=(lane>>4)*4+r][col=lane&15] per frag ----
  const int lr = lane & 15;
  const int rq = (lane >> 4) * 4;
#pragma unroll
  for (int i = 0; i < FM; ++i) {
#pragma unroll
    for (int j = 0; j < FN; ++j) {
      const int colb = n0 + wc * FN * 16 + j * 16 + lr;
      float bv = 0.f;
      if constexpr (EPI == EPI_F16B || EPI == EPI_SIG || EPI == EPI_RELU ||
                    EPI == EPI_QKV || EPI == EPI_VT || EPI == EPI_RESID ||
                    EPI == EPI_FC2 || EPI == EPI_OUT)
        bv = p.bias[colb];
#pragma unroll
      for (int r = 0; r < 4; ++r) {
        const int row = m0 + wr * FM * 16 + i * 16 + rq + r;
        float v = acc[i][j][r] + bv;
        if constexpr (EPI == EPI_SIG)  v = 1.f / (1.f + __expf(-v));
        if constexpr (EPI == EPI_RELU) v = fmaxf(v, 0.f);
        if constexpr (EPI == EPI_F16 || EPI == EPI_F16B || EPI == EPI_SIG || EPI == EPI_RELU) {
          ((f16*)p.C)[(long long)z * p.sC + (long long)row * p.ldc + colb] = (f16)v;
        } else if constexpr (EPI == EPI_SCORES) {
          ((float*)p.C)[(long long)z * p.sC + (long long)row * p.ldc + colb] = v * 0.125f;
        } else if constexpr (EPI == EPI_QKV) {
          const int b = row >> 10, l = row & 1023;
          const int h = colb >> 6, dk = colb & 63;
          ((f16*)p.C)[((((long long)b * HQ + h) * LQ + l) << 6) + dk] = (f16)v;
        } else if constexpr (EPI == EPI_VT) {
          const int b = row >> 10, l = row & 1023;
          const int h = colb >> 6, dk = colb & 63;
          ((f16*)p.C)[((((long long)b * HQ + h) * DKQ + dk) << 10) + l] = (f16)v;
        } else if constexpr (EPI == EPI_RESID) {
          const long long idx = (long long)row * DQ + colb;
          ((float*)p.C)[idx] = v;
          ((f16*)p.C2)[idx] = (f16)v;
        } else if constexpr (EPI == EPI_FC2) {
          const long long idx = (long long)row * DQ + colb;
          ((float*)p.C)[idx] = v + p.resid[idx];
        } else if constexpr (EPI == EPI_OUT) {
          ((float*)p.C)[(long long)row * DQ + colb] = v;
        }
      }
    }
  }
}

// Row softmax over L=1024 + halve column 0 (post-normalization), fp32 in, f16 out.
__global__ __launch_bounds__(256) void softmax_k(const float* __restrict__ S,
                                                 f16* __restrict__ P) {
  const long long row = (long long)blockIdx.y * 1024 + blockIdx.x;
  const int t = threadIdx.x;
  const float* s = S + row * 1024;
  float4 v = *(const float4*)(s + t * 4);
  float mx = fmaxf(fmaxf(v.x, v.y), fmaxf(v.z, v.w));
#pragma unroll
  for (int o = 1; o < 64; o <<= 1) mx = fmaxf(mx, __shfl_xor(mx, o));
  __shared__ float rm[4];
  if ((t & 63) == 0) rm[t >> 6] = mx;
  __syncthreads();
  mx = fmaxf(fmaxf(rm[0], rm[1]), fmaxf(rm[2], rm[3]));
  float e0 = __expf(v.x - mx), e1 = __expf(v.y - mx);
  float e2 = __expf(v.z - mx), e3 = __expf(v.w - mx);
  float sum = e0 + e1 + e2 + e3;
#pragma unroll
  for (int o = 1; o < 64; o <<= 1) sum += __shfl_xor(sum, o);
  __shared__ float rs[4];
  if ((t & 63) == 0) rs[t >> 6] = sum;
  __syncthreads();
  const float inv = 1.f / (rs[0] + rs[1] + rs[2] + rs[3]);
  if (t == 0) e0 *= 0.5f;  // column-0 intervention (applied after normalization)
  f16x4v o4 = {(f16)(e0 * inv), (f16)(e1 * inv), (f16)(e2 * inv), (f16)(e3 * inv)};
  *(f16x4v*)(P + row * 1024 + t * 4) = o4;
}

// LayerNorm over D=1024, fp32 in (h2 + residual already summed), f16 out.
__global__ __launch_bounds__(256) void ln_k(const float* __restrict__ pre,
                                            const float* __restrict__ w,
                                            const float* __restrict__ b,
                                            f16* __restrict__ out) {
  const long long row = blockIdx.x;
  const int t = threadIdx.x;
  const float* x = pre + row * 1024;
  float4 v = *(const float4*)(x + t * 4);
  float s = v.x + v.y + v.z + v.w;
  float s2 = v.x * v.x + v.y * v.y + v.z * v.z + v.w * v.w;
#pragma unroll
  for (int o = 1; o < 64; o <<= 1) { s += __shfl_xor(s, o); s2 += __shfl_xor(s2, o); }
  __shared__ float rs[4], rs2[4];
  if ((t & 63) == 0) { rs[t >> 6] = s; rs2[t >> 6] = s2; }
  __syncthreads();
  s = rs[0] + rs[1] + rs[2] + rs[3];
  s2 = rs2[0] + rs2[1] + rs2[2] + rs2[3];
  const float mean = s * (1.f / 1024.f);
  const float var = s2 * (1.f / 1024.f) - mean * mean;
  const float inv = rsqrtf(var + 1e-5f);
  f16x4v o4;
#pragma unroll
  for (int c = 0; c < 4; ++c) {
    const float xv = (&v.x)[c];
    o4[c] = (f16)((xv - mean) * inv * w[t * 4 + c] + b[t * 4 + c]);
  }
  *(f16x4v*)(out + row * 1024 + t * 4) = o4;
}

// f16 [B,L,D] -> [B,D,L] transpose via 64x64 LDS tile.
__global__ __launch_bounds__(256) void transpose_k(const f16* __restrict__ x,
                                                   f16* __restrict__ xt) {
  __shared__ f16 tile[64][65];
  const int c0 = blockIdx.x * 64;
  const int l0 = blockIdx.y * 64;
  const long long zb = (long long)blockIdx.z * (1024 * 1024);
  const int t = threadIdx.x;
#pragma unroll
  for (int it = 0; it < 16; ++it) {
    const int idx = it * 256 + t;
    const int r = idx >> 6, c = idx & 63;
    tile[r][c] = x[zb + (long long)(l0 + r) * 1024 + c0 + c];
  }
  __syncthreads();
#pragma unroll
  for (int it = 0; it < 16; ++it) {
    const int idx = it * 256 + t;
    const int r = idx >> 6, c = idx & 63;
    xt[zb + (long long)(c0 + r) * 1024 + l0 + c] = tile[c][r];
  }
}

__global__ __launch_bounds__(256) void cvt_f32_f16(const float* __restrict__ in,
                                                   f16* __restrict__ out, long long n4) {
  const long long i = (long long)blockIdx.x * 256 + threadIdx.x;
  if (i < n4) {
    float4 v = ((const float4*)in)[i];
    f16x4v o = {(f16)v.x, (f16)v.y, (f16)v.z, (f16)v.w};
    ((f16x4v*)out)[i] = o;
  }
}

extern "C" void kernel_launch(void* const* d_in, const int* in_sizes, int n_in,
                              void* d_out, int out_size, void* d_ws, size_t ws_size,
                              hipStream_t stream) {
  (void)in_sizes; (void)n_in; (void)out_size;
  const float* x_in  = (const float*)d_in[0];
  const float* emb_w = (const float*)d_in[1];
  const float* emb_b = (const float*)d_in[2];
  const float* cg_w  = (const float*)d_in[3];
  const float* cg_b  = (const float*)d_in[4];
  const float* wq    = (const float*)d_in[5];
  const float* bq    = (const float*)d_in[6];
  const float* wk    = (const float*)d_in[7];
  const float* bk    = (const float*)d_in[8];
  const float* wv    = (const float*)d_in[9];
  const float* bv    = (const float*)d_in[10];
  const float* wo    = (const float*)d_in[11];
  const float* bo    = (const float*)d_in[12];
  const float* fc1w  = (const float*)d_in[13];
  const float* fc1b  = (const float*)d_in[14];
  const float* fc2w  = (const float*)d_in[15];
  const float* fc2b  = (const float*)d_in[16];
  const float* lnw   = (const float*)d_in[17];
  const float* lnb   = (const float*)d_in[18];
  const float* outw  = (const float*)d_in[19];
  const float* outb  = (const float*)d_in[20];
  float* outp = (float*)d_out;

  const size_t M1 = 1024ull * 1024ull;
  char* wsp = (char*)d_ws;
  size_t off = 0;
  auto alloc = [&](size_t bytes) -> void* {
    void* r = wsp + off;
    off += (bytes + 255) & ~(size_t)255;
    return r;
  };

  // fp16 weights
  f16* embw_h = (f16*)alloc(M1 * 2);
  f16* outw_h = (f16*)alloc(M1 * 2);
  f16* cgw_h  = (f16*)alloc(6 * M1 * 2);
  f16* wq_h   = (f16*)alloc(6 * M1 * 2);
  f16* wk_h   = (f16*)alloc(6 * M1 * 2);
  f16* wv_h   = (f16*)alloc(6 * M1 * 2);
  f16* wo_h   = (f16*)alloc(6 * M1 * 2);
  f16* fc1_h  = (f16*)alloc(6 * M1 * 2);
  f16* fc2_h  = (f16*)alloc(6 * M1 * 2);
  // fp16 activations (2M elems each)
  f16* xh0   = (f16*)alloc(2 * M1 * 2);
  f16* xh    = (f16*)alloc(2 * M1 * 2);
  f16* xT    = (f16*)alloc(2 * M1 * 2);
  f16* cmb   = (f16*)alloc(2 * M1 * 2);
  f16* x2    = (f16*)alloc(2 * M1 * 2);
  f16* qb    = (f16*)alloc(2 * M1 * 2);
  f16* kbuf  = (f16*)alloc(2 * M1 * 2);
  f16* vT    = (f16*)alloc(2 * M1 * 2);
  f16* attnb = (f16*)alloc(2 * M1 * 2);
  f16* xf    = (f16*)alloc(2 * M1 * 2);
  f16* h1    = (f16*)alloc(2 * M1 * 2);
  // fp32 buffers
  float* resid = (float*)alloc(2 * M1 * 4);
  float* pre   = (float*)alloc(2 * M1 * 4);

  // attention chunk size G over the 32 (b,h) slices, sized to fit ws
  int G = 16;
  while (G > 1 && off + (size_t)G * M1 * 6 + 4096 > ws_size) G >>= 1;
  float* scoresb = (float*)alloc((size_t)G * M1 * 4);
  f16* Pb = (f16*)alloc((size_t)G * M1 * 2);

  // ---- fp32 -> fp16 conversions (every call; no cross-call state) ----
  auto cvt = [&](const float* src, f16* dst, size_t n) {
    cvt_f32_f16<<<dim3((unsigned)(n / 1024)), 256, 0, stream>>>(src, dst, (long long)(n / 4));
  };
  cvt(x_in, xh0, 2 * M1);
  cvt(emb_w, embw_h, M1);
  cvt(outw, outw_h, M1);
  cvt(cg_w, cgw_h, 6 * M1);
  cvt(wq, wq_h, 6 * M1);
  cvt(wk, wk_h, 6 * M1);
  cvt(wv, wv_h, 6 * M1);
  cvt(wo, wo_h, 6 * M1);
  cvt(fc1w, fc1_h, 6 * M1);
  cvt(fc2w, fc2_h, 6 * M1);

  // ---- embedding: xh = x @ emb_w^T + emb_b ----
  gemm_nt<128, 64, EPI_F16B><<<dim3(16, 16, 1), 256, 0, stream>>>(
      GP{xh0, embw_h, emb_b, xh, nullptr, nullptr, 1024, 1024, 1024, 1024, 0, 0, 0});

  for (int i = 0; i < 6; ++i) {
    const f16* cgwi = cgw_h + (size_t)i * M1;
    const f16* wqi = wq_h + (size_t)i * M1;
    const f16* wki = wk_h + (size_t)i * M1;
    const f16* wvi = wv_h + (size_t)i * M1;
    const f16* woi = wo_h + (size_t)i * M1;
    const f16* f1i = fc1_h + (size_t)i * M1;
    const f16* f2i = fc2_h + (size_t)i * M1;

    // xT = transpose(xh) per batch
    transpose_k<<<dim3(16, 16, 2), 256, 0, stream>>>(xh, xT);

    // cm = sigmoid(xh @ cg_w^T + cg_b)
    gemm_nt<128, 64, EPI_SIG><<<dim3(16, 16, 1), 256, 0, stream>>>(
        GP{xh, cgwi, cg_b + i * 1024, cmb, nullptr, nullptr,
           1024, 1024, 1024, 1024, 0, 0, 0});

    // x2[b] = cm[b] @ x[b]  (NT against xT)
    gemm_nt<128, 64, EPI_F16><<<dim3(16, 8, 2), 256, 0, stream>>>(
        GP{cmb, xT, nullptr, x2, nullptr, nullptr,
           1024, 1024, 1024, 1024, (long long)M1, (long long)M1, (long long)M1});

    // q, k -> [B,H,L,DK]; v -> [B,H,DK,L]
    gemm_nt<128, 64, EPI_QKV><<<dim3(16, 16, 1), 256, 0, stream>>>(
        GP{x2, wqi, bq + i * 1024, qb, nullptr, nullptr, 1024, 1024, 1024, 0, 0, 0, 0});
    gemm_nt<128, 64, EPI_QKV><<<dim3(16, 16, 1), 256, 0, stream>>>(
        GP{x2, wki, bk + i * 1024, kbuf, nullptr, nullptr, 1024, 1024, 1024, 0, 0, 0, 0});
    gemm_nt<128, 64, EPI_VT><<<dim3(16, 16, 1), 256, 0, stream>>>(
        GP{x2, wvi, bv + i * 1024, vT, nullptr, nullptr, 1024, 1024, 1024, 0, 0, 0, 0});

    // attention in chunks of G (b,h) slices
    for (int c = 0; c < 32 / G; ++c) {
      const int bh0 = c * G;
      const int b0 = bh0 >> 4, h0 = bh0 & 15;
      // scores = (q @ k^T) * 0.125   [G,L,L] fp32
      gemm_nt<128, 128, EPI_SCORES><<<dim3(8, 8, G), 256, 0, stream>>>(
          GP{qb + (size_t)bh0 * 65536, kbuf + (size_t)bh0 * 65536, nullptr,
             scoresb, nullptr, nullptr, 64, 64, 64, 1024,
             65536, 65536, (long long)M1});
      // P = softmax(scores) with col-0 halved
      softmax_k<<<dim3(1024, G), 256, 0, stream>>>(scoresb, Pb);
      // attn = P @ V (NT against vT), scattered into [B,L,D]
      gemm_nt<128, 64, EPI_F16><<<dim3(1, 8, G), 256, 0, stream>>>(
          GP{Pb, vT + (size_t)bh0 * 65536, nullptr,
             attnb + (size_t)b0 * M1 + (size_t)h0 * 64, nullptr, nullptr,
             1024, 1024, 1024, 1024, (long long)M1, 65536, 64});
    }

    // x = attn @ wo^T + bo  -> resid (fp32) + xf (fp16)
    gemm_nt<128, 64, EPI_RESID><<<dim3(16, 16, 1), 256, 0, stream>>>(
        GP{attnb, woi, bo + i * 1024, resid, xf, nullptr, 1024, 1024, 1024, 0, 0, 0, 0});
    // h1 = relu(xf @ fc1^T + fc1_b)
    gemm_nt<128, 64, EPI_RELU><<<dim3(16, 16, 1), 256, 0, stream>>>(
        GP{xf, f1i, fc1b + i * 1024, h1, nullptr, nullptr, 1024, 1024, 1024, 1024, 0, 0, 0});
    // pre = h1 @ fc2^T + fc2_b + resid
    gemm_nt<128, 64, EPI_FC2><<<dim3(16, 16, 1), 256, 0, stream>>>(
        GP{h1, f2i, fc2b + i * 1024, pre, nullptr, resid, 1024, 1024, 1024, 0, 0, 0, 0});
    // xh = layernorm(pre)
    ln_k<<<dim3(2048), 256, 0, stream>>>(pre, lnw + i * 1024, lnb + i * 1024, xh);
  }

  // out = xh @ out_w^T + out_b (fp32)
  gemm_nt<128, 64, EPI_OUT><<<dim3(16, 16, 1), 256, 0, stream>>>(
      GP{xh, outw_h, outb, outp, nullptr, nullptr, 1024, 1024, 1024, 0, 0, 0, 0});
}

// Round 2
// 1392.825 us; speedup vs baseline: 1.2192x; 1.2192x over previous
//
#include <hip/hip_runtime.h>

// CausaFormer forward on MI355X. fp16 MFMA GEMMs w/ fp32 accumulate.
// B=2, L=1024, D=1024, NL=6, H=16, DK=64.
// R2: m97-style GEMM (linear LDS + global_load_lds x16, 1 barrier/K-step)
//     + fused flash attention (online softmax, swizzled K/V LDS).

typedef _Float16 f16;
typedef _Float16 f16x8 __attribute__((ext_vector_type(8)));
typedef _Float16 f16x4v __attribute__((ext_vector_type(4)));
typedef float f32x4 __attribute__((ext_vector_type(4)));

#define LQ 1024
#define DQ 1024
#define HQ 16
#define DKQ 64

__device__ __forceinline__ void gload16(const void* g, void* l) {
  __builtin_amdgcn_global_load_lds((const __attribute__((address_space(1))) void*)g,
                                   (__attribute__((address_space(3))) void*)l, 16, 0, 0);
}

// Epilogue modes
enum {
  EPI_F16 = 0,   // f16 store, no bias           (cm@x)
  EPI_F16B,      // f16 store + bias             (embedding)
  EPI_SIG,       // sigmoid(v+bias) -> f16       (causal-graph gate)
  EPI_RELU,      // relu(v+bias) -> f16          (fc1)
  EPI_QKV,       // v+bias -> f16 at [B,H,L,DK]  (q,k proj)
  EPI_VT,        // v+bias -> f16 at [B,H,DK,L]  (v proj, pre-transposed)
  EPI_RESID,     // v+bias -> f32 C and f16 C2   (wo: residual + fc1 input)
  EPI_FC2,       // v+bias+resid -> f32          (fc2: pre-LN sum)
  EPI_OUT        // v+bias -> f32                (final projection)
};

struct GP {
  const f16* A; const f16* W; const float* bias;
  void* C; void* C2; const float* resid;
  int K; int lda; int ldw; int ldc;
  long long sA; long long sW; long long sC;
};

// NT GEMM: C[m][n] = epi( sum_k A[m][k] * W[n][k] ).
// 256 threads = 4 waves in 2x2. BK=32. Linear LDS [row][32 f16],
// global_load_lds dwordx4 staging, single barrier per K-step (m97 structure).
template<int BM, int BN, int EPI>
__global__ __launch_bounds__(256, 2) void gemm_nt(GP p) {
  constexpr int BK = 32;
  constexpr int ACH = BM / 16;     // 1KB staging chunks (64 lanes x 16B)
  constexpr int BCH = BN / 16;
  constexpr int FM = BM / 32;
  constexpr int FN = BN / 32;

  __shared__ __align__(16) f16 As[2][BM * BK];
  __shared__ __align__(16) f16 Bs[2][BN * BK];

  const int tid = threadIdx.x;
  const int lane = tid & 63;
  const int wid = tid >> 6;
  const int wr = wid >> 1;
  const int wc = wid & 1;
  const int z = blockIdx.z;
  const int m0 = blockIdx.y * BM;
  const int n0 = blockIdx.x * BN;

  const f16* Ab = p.A + (long long)z * p.sA;
  const f16* Wb = p.W + (long long)z * p.sW;

  auto stage = [&](int buf, int t) {
    const int ko = t * BK;
#pragma unroll
    for (int u = 0; u < ACH / 4; ++u) {
      const int c = u * 4 + wid;
      const int s = c * 64 + lane;
      const int row = s >> 2, c8 = s & 3;     // 4 x 16B chunks per 64B row
      gload16(Ab + (long long)(m0 + row) * p.lda + ko + c8 * 8, &As[buf][c * 512]);
    }
#pragma unroll
    for (int u = 0; u < BCH / 4; ++u) {
      const int c = u * 4 + wid;
      const int s = c * 64 + lane;
      const int row = s >> 2, c8 = s & 3;
      gload16(Wb + (long long)(n0 + row) * p.ldw + ko + c8 * 8, &Bs[buf][c * 512]);
    }
  };

  stage(0, 0);
  __syncthreads();

  f32x4 acc[FM][FN] = {};
  const int nt = p.K / BK;
  int cur = 0;
  for (int t = 0; t < nt; ++t) {
    if (t + 1 < nt) stage(cur ^ 1, t + 1);
    const int lr = lane & 15;
    const int kc16 = (lane >> 4) * 16;        // byte offset of k-chunk
    f16x8 fa[FM], fb[FN];
#pragma unroll
    for (int i = 0; i < FM; ++i)
      fa[i] = *(const f16x8*)((const char*)&As[cur][0] +
                              (wr * (FM * 16) + i * 16 + lr) * 64 + kc16);
#pragma unroll
    for (int j = 0; j < FN; ++j)
      fb[j] = *(const f16x8*)((const char*)&Bs[cur][0] +
                              (wc * (FN * 16) + j * 16 + lr) * 64 + kc16);
#pragma unroll
    for (int i = 0; i < FM; ++i)
#pragma unroll
      for (int j = 0; j < FN; ++j)
        acc[i][j] = __builtin_amdgcn_mfma_f32_16x16x32_f16(fa[i], fb[j], acc[i][j], 0, 0, 0);
    __syncthreads();
    cur ^= 1;
  }

  // ---- epilogue: D[row=(lane>>4)*4+r][col=lane&15] per frag ----
  const int lr = lane & 15;
  const int rq = (lane >> 4) * 4;
#pragma unroll
  for (int i = 0; i < FM; ++i) {
#pragma unroll
    for (int j = 0; j < FN; ++j) {
      const int colb = n0 + wc * FN * 16 + j * 16 + lr;
      float bv = 0.f;
      if constexpr (EPI != EPI_F16)
        bv = p.bias ? p.bias[colb] : 0.f;
#pragma unroll
      for (int r = 0; r < 4; ++r) {
        const int row = m0 + wr * FM * 16 + i * 16 + rq + r;
        float v = acc[i][j][r] + bv;
        if constexpr (EPI == EPI_SIG)  v = 1.f / (1.f + __expf(-v));
        if constexpr (EPI == EPI_RELU) v = fmaxf(v, 0.f);
        if constexpr (EPI == EPI_F16 || EPI == EPI_F16B || EPI == EPI_SIG || EPI == EPI_RELU) {
          ((f16*)p.C)[(long long)z * p.sC + (long long)row * p.ldc + colb] = (f16)v;
        } else if constexpr (EPI == EPI_QKV) {
          const int b = row >> 10, l = row & 1023;
          const int h = colb >> 6, dk = colb & 63;
          ((f16*)p.C)[((((long long)b * HQ + h) * LQ + l) << 6) + dk] = (f16)v;
        } else if constexpr (EPI == EPI_VT) {
          const int b = row >> 10, l = row & 1023;
          const int h = colb >> 6, dk = colb & 63;
          ((f16*)p.C)[((((long long)b * HQ + h) * DKQ + dk) << 10) + l] = (f16)v;
        } else if constexpr (EPI == EPI_RESID) {
          const long long idx = (long long)row * DQ + colb;
          ((float*)p.C)[idx] = v;
          ((f16*)p.C2)[idx] = (f16)v;
        } else if constexpr (EPI == EPI_FC2) {
          const long long idx = (long long)row * DQ + colb;
          ((float*)p.C)[idx] = v + p.resid[idx];
        } else if constexpr (EPI == EPI_OUT) {
          ((float*)p.C)[(long long)row * DQ + colb] = v;
        }
      }
    }
  }
}

// Fused flash attention. Grid (L/128, B*H), 256 threads = 4 waves.
// Wave w owns Q rows [w*32, w*32+32). K/V tiles of 64 staged in LDS
// (XOR-swizzled 16B chunks via pre-swizzled global source). Online softmax;
// row-sum via ones-column MFMA; col-0 halved post-normalization semantics.
__global__ __launch_bounds__(256, 1) void fattn(const f16* __restrict__ q,
                                                const f16* __restrict__ kk,
                                                const f16* __restrict__ vt,
                                                f16* __restrict__ out) {
  __shared__ __align__(16) f16 Ks[2][64 * 64];   // [j][dk] rows 128B, swizzled
  __shared__ __align__(16) f16 Vs[2][64 * 64];   // [dk][j] rows 128B, swizzled
  __shared__ __align__(16) f16 Ps[4][32 * 64];   // per-wave [i][j], swizzled

  const int tid = threadIdx.x;
  const int lane = tid & 63;
  const int wid = tid >> 6;
  const int lr = lane & 15;
  const int lg = lane >> 4;
  const int bh = blockIdx.y;
  const int b = bh >> 4, h = bh & 15;
  const int q0 = blockIdx.x * 128;

  const f16* qp = q + (long long)bh * 65536;
  const f16* kp = kk + (long long)bh * 65536;
  const f16* vp = vt + (long long)bh * 65536;

  // Q fragments (rows w*32 + mf*16 + lr, k = ks*32 + lg*8), straight from L2.
  f16x8 qf[2][2];
#pragma unroll
  for (int mf = 0; mf < 2; ++mf)
#pragma unroll
    for (int ks = 0; ks < 2; ++ks)
      qf[mf][ks] = *(const f16x8*)(qp + (long long)(q0 + wid * 32 + mf * 16 + lr) * 64 +
                                   ks * 32 + lg * 8);

  f32x4 o[2][4] = {};          // O[i][d] frags [mf][df]
  f32x4 ol[2] = {};            // row-sum accumulator (ones-column MFMA)
  float m_r[2][4];
#pragma unroll
  for (int mf = 0; mf < 2; ++mf)
#pragma unroll
    for (int r = 0; r < 4; ++r) m_r[mf][r] = -1e30f;

  const f16x8 ones = {(f16)1.f, (f16)1.f, (f16)1.f, (f16)1.f,
                      (f16)1.f, (f16)1.f, (f16)1.f, (f16)1.f};

  auto stage = [&](int buf, int t) {
    const int j0 = t * 64;
#pragma unroll
    for (int u = 0; u < 2; ++u) {
      const int c = u * 4 + wid;
      const int s = c * 64 + lane;
      const int row = s >> 3, ch = s & 7;      // 8 x 16B chunks per 128B row
      const int sch = (ch ^ (row & 7)) * 8;    // pre-swizzled source chunk
      gload16(kp + (long long)(j0 + row) * 64 + sch, &Ks[buf][c * 512]);
      gload16(vp + (long long)row * 1024 + j0 + sch, &Vs[buf][c * 512]);
    }
  };

  stage(0, 0);
  __syncthreads();

  constexpr float SCL = 0.125f * 1.44269504089f;  // 1/sqrt(64) * log2(e)
  int cur = 0;
  for (int t = 0; t < 16; ++t) {
    if (t + 1 < 16) stage(cur ^ 1, t + 1);

    // ---- QK^T ----
    f32x4 s[2][4] = {};
#pragma unroll
    for (int ks = 0; ks < 2; ++ks) {
      f16x8 fb[4];
#pragma unroll
      for (int jf = 0; jf < 4; ++jf) {
        const int j = jf * 16 + lr;
        const int ch = ks * 4 + lg;
        fb[jf] = *(const f16x8*)((const char*)&Ks[cur][0] + j * 128 + ((ch ^ (j & 7)) << 4));
      }
#pragma unroll
      for (int mf = 0; mf < 2; ++mf)
#pragma unroll
        for (int jf = 0; jf < 4; ++jf)
          s[mf][jf] = __builtin_amdgcn_mfma_f32_16x16x32_f16(qf[mf][ks], fb[jf], s[mf][jf], 0, 0, 0);
    }

    // ---- online softmax (log2 domain) ----
#pragma unroll
    for (int mf = 0; mf < 2; ++mf)
#pragma unroll
      for (int jf = 0; jf < 4; ++jf)
#pragma unroll
        for (int r = 0; r < 4; ++r) s[mf][jf][r] *= SCL;

#pragma unroll
    for (int mf = 0; mf < 2; ++mf) {
#pragma unroll
      for (int r = 0; r < 4; ++r) {
        float pm = fmaxf(fmaxf(s[mf][0][r], s[mf][1][r]), fmaxf(s[mf][2][r], s[mf][3][r]));
#pragma unroll
        for (int off = 1; off < 16; off <<= 1) pm = fmaxf(pm, __shfl_xor(pm, off));
        const float mn = fmaxf(m_r[mf][r], pm);
        const float sf = __builtin_exp2f(m_r[mf][r] - mn);
        m_r[mf][r] = mn;
        ol[mf][r] *= sf;
#pragma unroll
        for (int df = 0; df < 4; ++df) o[mf][df][r] *= sf;
#pragma unroll
        for (int jf = 0; jf < 4; ++jf)
          s[mf][jf][r] = __builtin_exp2f(s[mf][jf][r] - mn);
      }
    }
    // column-0 intervention: halve P for PV; denominator keeps full sum
    // (corrected after the ones-MFMA below).
    if (t == 0 && lr == 0) {
#pragma unroll
      for (int mf = 0; mf < 2; ++mf)
#pragma unroll
        for (int r = 0; r < 4; ++r) s[mf][0][r] *= 0.5f;
    }

    // ---- P -> LDS (f16, swizzled) ----
#pragma unroll
    for (int mf = 0; mf < 2; ++mf)
#pragma unroll
      for (int jf = 0; jf < 4; ++jf)
#pragma unroll
        for (int r = 0; r < 4; ++r) {
          const int i = mf * 16 + lg * 4 + r;
          const int jc = jf * 16 + lr;
          const int sb = i * 128 + (((jc >> 3) ^ (i & 7)) << 4) + (jc & 7) * 2;
          *(f16*)((char*)&Ps[wid][0] + sb) = (f16)s[mf][jf][r];
        }
    asm volatile("s_waitcnt lgkmcnt(0)" ::: "memory");

    // ---- PV (+ ones-column row-sum) ----
#pragma unroll
    for (int ks = 0; ks < 2; ++ks) {
      f16x8 fa[2], fv[4];
#pragma unroll
      for (int mf = 0; mf < 2; ++mf) {
        const int i = mf * 16 + lr;
        const int ch = ks * 4 + lg;
        fa[mf] = *(const f16x8*)((const char*)&Ps[wid][0] + i * 128 + ((ch ^ (i & 7)) << 4));
      }
#pragma unroll
      for (int df = 0; df < 4; ++df) {
        const int d = df * 16 + lr;
        const int ch = ks * 4 + lg;
        fv[df] = *(const f16x8*)((const char*)&Vs[cur][0] + d * 128 + ((ch ^ (d & 7)) << 4));
      }
#pragma unroll
      for (int mf = 0; mf < 2; ++mf) {
#pragma unroll
        for (int df = 0; df < 4; ++df)
          o[mf][df] = __builtin_amdgcn_mfma_f32_16x16x32_f16(fa[mf], fv[df], o[mf][df], 0, 0, 0);
        ol[mf] = __builtin_amdgcn_mfma_f32_16x16x32_f16(fa[mf], ones, ol[mf], 0, 0, 0);
      }
    }
    // denominator correction for halved col 0: add back 0.5*p0 (= halved value)
    if (t == 0) {
#pragma unroll
      for (int mf = 0; mf < 2; ++mf)
#pragma unroll
        for (int r = 0; r < 4; ++r) {
          const float hv = __shfl(s[mf][0][r], lane & 48);  // value at lr==0 of this group
          ol[mf][r] += hv;
        }
    }
    __syncthreads();
    cur ^= 1;
  }

  // ---- normalize + scatter to [B,L,D] ----
#pragma unroll
  for (int mf = 0; mf < 2; ++mf)
#pragma unroll
    for (int r = 0; r < 4; ++r) {
      const float inv = 1.f / ol[mf][r];
      const long long row = q0 + wid * 32 + mf * 16 + lg * 4 + r;
#pragma unroll
      for (int df = 0; df < 4; ++df)
        out[(long long)b * 1048576 + row * 1024 + h * 64 + df * 16 + lr] =
            (f16)(o[mf][df][r] * inv);
    }
}

// LayerNorm over D=1024, fp32 in, f16 out.
__global__ __launch_bounds__(256) void ln_k(const float* __restrict__ pre,
                                            const float* __restrict__ w,
                                            const float* __restrict__ b,
                                            f16* __restrict__ out) {
  const long long row = blockIdx.x;
  const int t = threadIdx.x;
  const float* x = pre + row * 1024;
  float4 v = *(const float4*)(x + t * 4);
  float s = v.x + v.y + v.z + v.w;
  float s2 = v.x * v.x + v.y * v.y + v.z * v.z + v.w * v.w;
#pragma unroll
  for (int o = 1; o < 64; o <<= 1) { s += __shfl_xor(s, o); s2 += __shfl_xor(s2, o); }
  __shared__ float rs[4], rs2[4];
  if ((t & 63) == 0) { rs[t >> 6] = s; rs2[t >> 6] = s2; }
  __syncthreads();
  s = rs[0] + rs[1] + rs[2] + rs[3];
  s2 = rs2[0] + rs2[1] + rs2[2] + rs2[3];
  const float mean = s * (1.f / 1024.f);
  const float var = s2 * (1.f / 1024.f) - mean * mean;
  const float inv = rsqrtf(var + 1e-5f);
  f16x4v o4;
#pragma unroll
  for (int c = 0; c < 4; ++c) {
    const float xv = (&v.x)[c];
    o4[c] = (f16)((xv - mean) * inv * w[t * 4 + c] + b[t * 4 + c]);
  }
  *(f16x4v*)(out + row * 1024 + t * 4) = o4;
}

// f16 [B,L,D] -> [B,D,L] transpose via 64x64 LDS tile.
__global__ __launch_bounds__(256) void transpose_k(const f16* __restrict__ x,
                                                   f16* __restrict__ xt) {
  __shared__ f16 tile[64][65];
  const int c0 = blockIdx.x * 64;
  const int l0 = blockIdx.y * 64;
  const long long zb = (long long)blockIdx.z * (1024 * 1024);
  const int t = threadIdx.x;
#pragma unroll
  for (int it = 0; it < 16; ++it) {
    const int idx = it * 256 + t;
    const int r = idx >> 6, c = idx & 63;
    tile[r][c] = x[zb + (long long)(l0 + r) * 1024 + c0 + c];
  }
  __syncthreads();
#pragma unroll
  for (int it = 0; it < 16; ++it) {
    const int idx = it * 256 + t;
    const int r = idx >> 6, c = idx & 63;
    xt[zb + (long long)(c0 + r) * 1024 + l0 + c] = tile[c][r];
  }
}

__global__ __launch_bounds__(256) void cvt_f32_f16(const float* __restrict__ in,
                                                   f16* __restrict__ out, long long n4) {
  const long long i = (long long)blockIdx.x * 256 + threadIdx.x;
  if (i < n4) {
    float4 v = ((const float4*)in)[i];
    f16x4v o = {(f16)v.x, (f16)v.y, (f16)v.z, (f16)v.w};
    ((f16x4v*)out)[i] = o;
  }
}

extern "C" void kernel_launch(void* const* d_in, const int* in_sizes, int n_in,
                              void* d_out, int out_size, void* d_ws, size_t ws_size,
                              hipStream_t stream) {
  (void)in_sizes; (void)n_in; (void)out_size; (void)ws_size;
  const float* x_in  = (const float*)d_in[0];
  const float* emb_w = (const float*)d_in[1];
  const float* emb_b = (const float*)d_in[2];
  const float* cg_w  = (const float*)d_in[3];
  const float* cg_b  = (const float*)d_in[4];
  const float* wq    = (const float*)d_in[5];
  const float* bq    = (const float*)d_in[6];
  const float* wk    = (const float*)d_in[7];
  const float* bk    = (const float*)d_in[8];
  const float* wv    = (const float*)d_in[9];
  const float* bv    = (const float*)d_in[10];
  const float* wo    = (const float*)d_in[11];
  const float* bo    = (const float*)d_in[12];
  const float* fc1w  = (const float*)d_in[13];
  const float* fc1b  = (const float*)d_in[14];
  const float* fc2w  = (const float*)d_in[15];
  const float* fc2b  = (const float*)d_in[16];
  const float* lnw   = (const float*)d_in[17];
  const float* lnb   = (const float*)d_in[18];
  const float* outw  = (const float*)d_in[19];
  const float* outb  = (const float*)d_in[20];
  float* outp = (float*)d_out;

  const size_t M1 = 1024ull * 1024ull;
  char* wsp = (char*)d_ws;
  size_t off = 0;
  auto alloc = [&](size_t bytes) -> void* {
    void* r = wsp + off;
    off += (bytes + 255) & ~(size_t)255;
    return r;
  };

  // fp16 weights
  f16* embw_h = (f16*)alloc(M1 * 2);
  f16* outw_h = (f16*)alloc(M1 * 2);
  f16* cgw_h  = (f16*)alloc(6 * M1 * 2);
  f16* wq_h   = (f16*)alloc(6 * M1 * 2);
  f16* wk_h   = (f16*)alloc(6 * M1 * 2);
  f16* wv_h   = (f16*)alloc(6 * M1 * 2);
  f16* wo_h   = (f16*)alloc(6 * M1 * 2);
  f16* fc1_h  = (f16*)alloc(6 * M1 * 2);
  f16* fc2_h  = (f16*)alloc(6 * M1 * 2);
  // fp16 activations
  f16* xh0   = (f16*)alloc(2 * M1 * 2);
  f16* xh    = (f16*)alloc(2 * M1 * 2);
  f16* xT    = (f16*)alloc(2 * M1 * 2);
  f16* cmb   = (f16*)alloc(2 * M1 * 2);
  f16* x2    = (f16*)alloc(2 * M1 * 2);
  f16* qb    = (f16*)alloc(2 * M1 * 2);
  f16* kbuf  = (f16*)alloc(2 * M1 * 2);
  f16* vT    = (f16*)alloc(2 * M1 * 2);
  f16* attnb = (f16*)alloc(2 * M1 * 2);
  f16* xf    = (f16*)alloc(2 * M1 * 2);
  f16* h1    = (f16*)alloc(2 * M1 * 2);
  // fp32 buffers
  float* resid = (float*)alloc(2 * M1 * 4);
  float* pre   = (float*)alloc(2 * M1 * 4);

  auto cvt = [&](const float* src, f16* dst, size_t n) {
    cvt_f32_f16<<<dim3((unsigned)(n / 1024)), 256, 0, stream>>>(src, dst, (long long)(n / 4));
  };
  cvt(x_in, xh0, 2 * M1);
  cvt(emb_w, embw_h, M1);
  cvt(outw, outw_h, M1);
  cvt(cg_w, cgw_h, 6 * M1);
  cvt(wq, wq_h, 6 * M1);
  cvt(wk, wk_h, 6 * M1);
  cvt(wv, wv_h, 6 * M1);
  cvt(wo, wo_h, 6 * M1);
  cvt(fc1w, fc1_h, 6 * M1);
  cvt(fc2w, fc2_h, 6 * M1);

  // embedding: xh = x @ emb_w^T + emb_b
  gemm_nt<128, 64, EPI_F16B><<<dim3(16, 16, 1), 256, 0, stream>>>(
      GP{xh0, embw_h, emb_b, xh, nullptr, nullptr, 1024, 1024, 1024, 1024, 0, 0, 0});

  for (int i = 0; i < 6; ++i) {
    const f16* cgwi = cgw_h + (size_t)i * M1;
    const f16* wqi = wq_h + (size_t)i * M1;
    const f16* wki = wk_h + (size_t)i * M1;
    const f16* wvi = wv_h + (size_t)i * M1;
    const f16* woi = wo_h + (size_t)i * M1;
    const f16* f1i = fc1_h + (size_t)i * M1;
    const f16* f2i = fc2_h + (size_t)i * M1;

    transpose_k<<<dim3(16, 16, 2), 256, 0, stream>>>(xh, xT);

    // cm = sigmoid(xh @ cg_w^T + cg_b)
    gemm_nt<128, 64, EPI_SIG><<<dim3(16, 16, 1), 256, 0, stream>>>(
        GP{xh, cgwi, cg_b + i * 1024, cmb, nullptr, nullptr,
           1024, 1024, 1024, 1024, 0, 0, 0});

    // x2[b] = cm[b] @ x[b]  (NT against xT)
    gemm_nt<128, 64, EPI_F16><<<dim3(16, 8, 2), 256, 0, stream>>>(
        GP{cmb, xT, nullptr, x2, nullptr, nullptr,
           1024, 1024, 1024, 1024, (long long)M1, (long long)M1, (long long)M1});

    // q, k -> [B,H,L,DK]; v -> [B,H,DK,L]
    gemm_nt<128, 64, EPI_QKV><<<dim3(16, 16, 1), 256, 0, stream>>>(
        GP{x2, wqi, bq + i * 1024, qb, nullptr, nullptr, 1024, 1024, 1024, 0, 0, 0, 0});
    gemm_nt<128, 64, EPI_QKV><<<dim3(16, 16, 1), 256, 0, stream>>>(
        GP{x2, wki, bk + i * 1024, kbuf, nullptr, nullptr, 1024, 1024, 1024, 0, 0, 0, 0});
    gemm_nt<128, 64, EPI_VT><<<dim3(16, 16, 1), 256, 0, stream>>>(
        GP{x2, wvi, bv + i * 1024, vT, nullptr, nullptr, 1024, 1024, 1024, 0, 0, 0, 0});

    // fused attention
    fattn<<<dim3(8, 32), 256, 0, stream>>>(qb, kbuf, vT, attnb);

    // x = attn @ wo^T + bo  -> resid (fp32) + xf (fp16)
    gemm_nt<128, 64, EPI_RESID><<<dim3(16, 16, 1), 256, 0, stream>>>(
        GP{attnb, woi, bo + i * 1024, resid, xf, nullptr, 1024, 1024, 1024, 0, 0, 0, 0});
    gemm_nt<128, 64, EPI_RELU><<<dim3(16, 16, 1), 256, 0, stream>>>(
        GP{xf, f1i, fc1b + i * 1024, h1, nullptr, nullptr, 1024, 1024, 1024, 1024, 0, 0, 0});
    gemm_nt<128, 64, EPI_FC2><<<dim3(16, 16, 1), 256, 0, stream>>>(
        GP{h1, f2i, fc2b + i * 1024, pre, nullptr, resid, 1024, 1024, 1024, 0, 0, 0, 0});
    ln_k<<<dim3(2048), 256, 0, stream>>>(pre, lnw + i * 1024, lnb + i * 1024, xh);
  }

  gemm_nt<128, 64, EPI_OUT><<<dim3(16, 16, 1), 256, 0, stream>>>(
      GP{xh, outw_h, outb, outp, nullptr, nullptr, 1024, 1024, 1024, 0, 0, 0, 0});
}

// Round 3
// 957.578 us; speedup vs baseline: 1.7734x; 1.4545x over previous
//
#include <hip/hip_runtime.h>

// CausaFormer forward on MI355X. fp16 MFMA GEMMs w/ fp32 accumulate.
// B=2, L=1024, D=1024, NL=6, H=16, DK=64.
// R3: occupancy push — 64x64x64 swizzled GEMM tiles (grid >=512), fused QKV
//     GEMM (grid 1536), fattn QBLK=64 (grid 512).

typedef _Float16 f16;
typedef _Float16 f16x8 __attribute__((ext_vector_type(8)));
typedef _Float16 f16x4v __attribute__((ext_vector_type(4)));
typedef float f32x4 __attribute__((ext_vector_type(4)));

__device__ __forceinline__ void gload16(const void* g, void* l) {
  __builtin_amdgcn_global_load_lds((const __attribute__((address_space(1))) void*)g,
                                   (__attribute__((address_space(3))) void*)l, 16, 0, 0);
}

// Epilogue modes
enum {
  EPI_F16 = 0,   // f16 store, no bias           (cm@x)
  EPI_F16B,      // f16 store + bias             (embedding)
  EPI_SIG,       // sigmoid(v+bias) -> f16       (causal-graph gate)
  EPI_RELU,      // relu(v+bias) -> f16          (fc1)
  EPI_QKV3,      // fused q/k/v: q,k -> [B,H,L,DK]; v -> [B,H,DK,L]
  EPI_RESID,     // v+bias -> f32 C and f16 C2   (wo: residual + fc1 input)
  EPI_FC2,       // v+bias+resid -> f32          (fc2: pre-LN sum)
  EPI_OUT        // v+bias -> f32                (final projection)
};

struct GP {
  const f16* A; const f16* W; const f16* W2; const f16* W3;
  const float* bias; const float* bias2; const float* bias3;
  void* C; void* C2; void* C3; const float* resid;
  int K; int lda; int ldw; int ldc;
  long long sA; long long sW; long long sC;
};

// NT GEMM: C[m][n] = epi( sum_k A[m][k] * W[n][k] ).
// 64x64 tile, BK=64, 256 threads = 4 waves in 2x2 (wave tile 32x32).
// LDS rows are 128B -> XOR-swizzle 16B chunks (linear dest + pre-swizzled
// global source + swizzled ds_read; conflict-free, 2-way max).
template<int EPI>
__global__ __launch_bounds__(256, 4) void gemm_nt(GP p) {
  constexpr int BM = 64, BN = 64, BK = 64;
  constexpr int FM = 2, FN = 2;

  __shared__ __align__(16) f16 As[2][BM * BK];
  __shared__ __align__(16) f16 Bs[2][BN * BK];

  const int tid = threadIdx.x;
  const int lane = tid & 63;
  const int wid = tid >> 6;
  const int wr = wid >> 1;
  const int wc = wid & 1;
  const int z = blockIdx.z;
  const int m0 = blockIdx.y * BM;
  const int n0 = blockIdx.x * BN;

  const f16* Ab = p.A + (long long)z * p.sA;
  const f16* Wb;
  int n0l = n0, nm = 0;
  if constexpr (EPI == EPI_QKV3) {
    nm = n0 >> 10;
    Wb = (nm == 0 ? p.W : nm == 1 ? p.W2 : p.W3);
    n0l = n0 & 1023;
  } else {
    Wb = p.W + (long long)z * p.sW;
  }

  auto stage = [&](int buf, int t) {
    const int ko = t * BK;
#pragma unroll
    for (int u = 0; u < 2; ++u) {
      const int c = u * 4 + wid;
      const int s = c * 64 + lane;
      const int row = s >> 3, ch = s & 7;          // 8 x 16B chunks per 128B row
      const int sk = ((ch ^ (row & 7)) << 3);      // pre-swizzled source k-offset
      gload16(Ab + (long long)(m0 + row) * p.lda + ko + sk, &As[buf][c * 512]);
      gload16(Wb + (long long)(n0l + row) * p.ldw + ko + sk, &Bs[buf][c * 512]);
    }
  };

  stage(0, 0);
  __syncthreads();

  f32x4 acc[FM][FN] = {};
  const int nt = p.K / BK;
  const int lr = lane & 15;
  const int lg = lane >> 4;
  int cur = 0;
  for (int t = 0; t < nt; ++t) {
    if (t + 1 < nt) stage(cur ^ 1, t + 1);
#pragma unroll
    for (int ks = 0; ks < 2; ++ks) {
      f16x8 fa[FM], fb[FN];
#pragma unroll
      for (int i = 0; i < FM; ++i) {
        const int r = wr * 32 + i * 16 + lr;
        fa[i] = *(const f16x8*)((const char*)&As[cur][0] + r * 128 +
                                (((ks * 4 + lg) ^ (r & 7)) << 4));
      }
#pragma unroll
      for (int j = 0; j < FN; ++j) {
        const int r = wc * 32 + j * 16 + lr;
        fb[j] = *(const f16x8*)((const char*)&Bs[cur][0] + r * 128 +
                                (((ks * 4 + lg) ^ (r & 7)) << 4));
      }
#pragma unroll
      for (int i = 0; i < FM; ++i)
#pragma unroll
        for (int j = 0; j < FN; ++j)
          acc[i][j] = __builtin_amdgcn_mfma_f32_16x16x32_f16(fa[i], fb[j], acc[i][j], 0, 0, 0);
    }
    __syncthreads();
    cur ^= 1;
  }

  // ---- epilogue: D[row=(lane>>4)*4+r][col=lane&15] per frag ----
  const int rq = lg * 4;
  const float* bp = p.bias;
  if constexpr (EPI == EPI_QKV3)
    bp = nm == 0 ? p.bias : nm == 1 ? p.bias2 : p.bias3;
#pragma unroll
  for (int i = 0; i < FM; ++i) {
#pragma unroll
    for (int j = 0; j < FN; ++j) {
      const int colb = n0l + wc * 32 + j * 16 + lr;
      float bv = 0.f;
      if constexpr (EPI != EPI_F16) bv = bp ? bp[colb] : 0.f;
#pragma unroll
      for (int r = 0; r < 4; ++r) {
        const int row = m0 + wr * 32 + i * 16 + rq + r;
        float v = acc[i][j][r] + bv;
        if constexpr (EPI == EPI_SIG)  v = 1.f / (1.f + __expf(-v));
        if constexpr (EPI == EPI_RELU) v = fmaxf(v, 0.f);
        if constexpr (EPI == EPI_F16 || EPI == EPI_F16B || EPI == EPI_SIG || EPI == EPI_RELU) {
          ((f16*)p.C)[(long long)z * p.sC + (long long)row * p.ldc + colb] = (f16)v;
        } else if constexpr (EPI == EPI_QKV3) {
          const int b = row >> 10, l = row & 1023;
          const int h = colb >> 6, dk = colb & 63;
          if (nm == 2)
            ((f16*)p.C3)[((((long long)b * 16 + h) * 64 + dk) << 10) + l] = (f16)v;
          else
            ((f16*)(nm == 0 ? p.C : p.C2))[((((long long)b * 16 + h) * 1024 + l) << 6) + dk] = (f16)v;
        } else if constexpr (EPI == EPI_RESID) {
          const long long idx = (long long)row * 1024 + colb;
          ((float*)p.C)[idx] = v;
          ((f16*)p.C2)[idx] = (f16)v;
        } else if constexpr (EPI == EPI_FC2) {
          const long long idx = (long long)row * 1024 + colb;
          ((float*)p.C)[idx] = v + p.resid[idx];
        } else if constexpr (EPI == EPI_OUT) {
          ((float*)p.C)[(long long)row * 1024 + colb] = v;
        }
      }
    }
  }
}

// Fused flash attention. Grid (L/64, B*H), 256 threads = 4 waves.
// Wave w owns Q rows [w*16, w*16+16). K/V tiles of 64 in swizzled LDS dbuf.
__global__ __launch_bounds__(256, 2) void fattn(const f16* __restrict__ q,
                                                const f16* __restrict__ kk,
                                                const f16* __restrict__ vt,
                                                f16* __restrict__ out) {
  __shared__ __align__(16) f16 Ks[2][64 * 64];   // [j][dk] rows 128B, swizzled
  __shared__ __align__(16) f16 Vs[2][64 * 64];   // [dk][j] rows 128B, swizzled
  __shared__ __align__(16) f16 Ps[4][16 * 64];   // per-wave [i][j], swizzled

  const int tid = threadIdx.x;
  const int lane = tid & 63;
  const int wid = tid >> 6;
  const int lr = lane & 15;
  const int lg = lane >> 4;
  const int bh = blockIdx.y;
  const int b = bh >> 4, h = bh & 15;
  const int q0 = blockIdx.x * 64;

  const f16* qp = q + (long long)bh * 65536;
  const f16* kp = kk + (long long)bh * 65536;
  const f16* vp = vt + (long long)bh * 65536;

  f16x8 qf[2];
#pragma unroll
  for (int ks = 0; ks < 2; ++ks)
    qf[ks] = *(const f16x8*)(qp + (long long)(q0 + wid * 16 + lr) * 64 + ks * 32 + lg * 8);

  f32x4 o[4] = {};
  f32x4 ol = {};
  float m_r[4] = {-1e30f, -1e30f, -1e30f, -1e30f};

  const f16x8 ones = {(f16)1.f, (f16)1.f, (f16)1.f, (f16)1.f,
                      (f16)1.f, (f16)1.f, (f16)1.f, (f16)1.f};

  auto stage = [&](int buf, int t) {
    const int j0 = t * 64;
#pragma unroll
    for (int u = 0; u < 2; ++u) {
      const int c = u * 4 + wid;
      const int s = c * 64 + lane;
      const int row = s >> 3, ch = s & 7;
      const int sch = (ch ^ (row & 7)) * 8;
      gload16(kp + (long long)(j0 + row) * 64 + sch, &Ks[buf][c * 512]);
      gload16(vp + (long long)row * 1024 + j0 + sch, &Vs[buf][c * 512]);
    }
  };

  stage(0, 0);
  __syncthreads();

  constexpr float SCL = 0.125f * 1.44269504089f;  // 1/sqrt(64) * log2(e)
  int cur = 0;
  for (int t = 0; t < 16; ++t) {
    if (t + 1 < 16) stage(cur ^ 1, t + 1);

    // ---- QK^T ----
    f32x4 s[4] = {};
#pragma unroll
    for (int ks = 0; ks < 2; ++ks) {
      f16x8 fb[4];
#pragma unroll
      for (int jf = 0; jf < 4; ++jf) {
        const int j = jf * 16 + lr;
        fb[jf] = *(const f16x8*)((const char*)&Ks[cur][0] + j * 128 +
                                 (((ks * 4 + lg) ^ (j & 7)) << 4));
      }
#pragma unroll
      for (int jf = 0; jf < 4; ++jf)
        s[jf] = __builtin_amdgcn_mfma_f32_16x16x32_f16(qf[ks], fb[jf], s[jf], 0, 0, 0);
    }

    // ---- online softmax (log2 domain) ----
#pragma unroll
    for (int jf = 0; jf < 4; ++jf)
#pragma unroll
      for (int r = 0; r < 4; ++r) s[jf][r] *= SCL;

#pragma unroll
    for (int r = 0; r < 4; ++r) {
      float pm = fmaxf(fmaxf(s[0][r], s[1][r]), fmaxf(s[2][r], s[3][r]));
#pragma unroll
      for (int off = 1; off < 16; off <<= 1) pm = fmaxf(pm, __shfl_xor(pm, off));
      const float mn = fmaxf(m_r[r], pm);
      const float sf = __builtin_exp2f(m_r[r] - mn);
      m_r[r] = mn;
      ol[r] *= sf;
#pragma unroll
      for (int df = 0; df < 4; ++df) o[df][r] *= sf;
#pragma unroll
      for (int jf = 0; jf < 4; ++jf)
        s[jf][r] = __builtin_exp2f(s[jf][r] - mn);
    }
    // column-0 intervention: halve P for PV; denominator keeps full sum.
    if (t == 0 && lr == 0) {
#pragma unroll
      for (int r = 0; r < 4; ++r) s[0][r] *= 0.5f;
    }

    // ---- P -> LDS (f16, swizzled) ----
#pragma unroll
    for (int jf = 0; jf < 4; ++jf)
#pragma unroll
      for (int r = 0; r < 4; ++r) {
        const int i = lg * 4 + r;
        const int jc = jf * 16 + lr;
        const int sb = i * 128 + (((jc >> 3) ^ (i & 7)) << 4) + (jc & 7) * 2;
        *(f16*)((char*)&Ps[wid][0] + sb) = (f16)s[jf][r];
      }
    asm volatile("s_waitcnt lgkmcnt(0)" ::: "memory");
    __builtin_amdgcn_sched_barrier(0);

    // ---- PV (+ ones-column row-sum) ----
#pragma unroll
    for (int ks = 0; ks < 2; ++ks) {
      f16x8 fa, fv[4];
      fa = *(const f16x8*)((const char*)&Ps[wid][0] + lr * 128 +
                           (((ks * 4 + lg) ^ (lr & 7)) << 4));
#pragma unroll
      for (int df = 0; df < 4; ++df) {
        const int d = df * 16 + lr;
        fv[df] = *(const f16x8*)((const char*)&Vs[cur][0] + d * 128 +
                                 (((ks * 4 + lg) ^ (d & 7)) << 4));
      }
#pragma unroll
      for (int df = 0; df < 4; ++df)
        o[df] = __builtin_amdgcn_mfma_f32_16x16x32_f16(fa, fv[df], o[df], 0, 0, 0);
      ol = __builtin_amdgcn_mfma_f32_16x16x32_f16(fa, ones, ol, 0, 0, 0);
    }
    // denominator correction for halved col 0: add back the halved value.
    if (t == 0) {
#pragma unroll
      for (int r = 0; r < 4; ++r)
        ol[r] += __shfl(s[0][r], lane & 48);
    }
    __syncthreads();
    cur ^= 1;
  }

  // ---- normalize + scatter to [B,L,D] ----
#pragma unroll
  for (int r = 0; r < 4; ++r) {
    const float inv = 1.f / ol[r];
    const long long row = q0 + wid * 16 + lg * 4 + r;
#pragma unroll
    for (int df = 0; df < 4; ++df)
      out[(long long)b * 1048576 + row * 1024 + h * 64 + df * 16 + lr] =
          (f16)(o[df][r] * inv);
  }
}

// LayerNorm over D=1024, fp32 in, f16 out.
__global__ __launch_bounds__(256) void ln_k(const float* __restrict__ pre,
                                            const float* __restrict__ w,
                                            const float* __restrict__ b,
                                            f16* __restrict__ out) {
  const long long row = blockIdx.x;
  const int t = threadIdx.x;
  const float* x = pre + row * 1024;
  float4 v = *(const float4*)(x + t * 4);
  float s = v.x + v.y + v.z + v.w;
  float s2 = v.x * v.x + v.y * v.y + v.z * v.z + v.w * v.w;
#pragma unroll
  for (int o = 1; o < 64; o <<= 1) { s += __shfl_xor(s, o); s2 += __shfl_xor(s2, o); }
  __shared__ float rs[4], rs2[4];
  if ((t & 63) == 0) { rs[t >> 6] = s; rs2[t >> 6] = s2; }
  __syncthreads();
  s = rs[0] + rs[1] + rs[2] + rs[3];
  s2 = rs2[0] + rs2[1] + rs2[2] + rs2[3];
  const float mean = s * (1.f / 1024.f);
  const float var = s2 * (1.f / 1024.f) - mean * mean;
  const float inv = rsqrtf(var + 1e-5f);
  f16x4v o4;
#pragma unroll
  for (int c = 0; c < 4; ++c) {
    const float xv = (&v.x)[c];
    o4[c] = (f16)((xv - mean) * inv * w[t * 4 + c] + b[t * 4 + c]);
  }
  *(f16x4v*)(out + row * 1024 + t * 4) = o4;
}

// f16 [B,L,D] -> [B,D,L] transpose via 64x64 LDS tile.
__global__ __launch_bounds__(256) void transpose_k(const f16* __restrict__ x,
                                                   f16* __restrict__ xt) {
  __shared__ f16 tile[64][65];
  const int c0 = blockIdx.x * 64;
  const int l0 = blockIdx.y * 64;
  const long long zb = (long long)blockIdx.z * (1024 * 1024);
  const int t = threadIdx.x;
#pragma unroll
  for (int it = 0; it < 16; ++it) {
    const int idx = it * 256 + t;
    const int r = idx >> 6, c = idx & 63;
    tile[r][c] = x[zb + (long long)(l0 + r) * 1024 + c0 + c];
  }
  __syncthreads();
#pragma unroll
  for (int it = 0; it < 16; ++it) {
    const int idx = it * 256 + t;
    const int r = idx >> 6, c = idx & 63;
    xt[zb + (long long)(c0 + r) * 1024 + l0 + c] = tile[c][r];
  }
}

__global__ __launch_bounds__(256) void cvt_f32_f16(const float* __restrict__ in,
                                                   f16* __restrict__ out, long long n4) {
  const long long i = (long long)blockIdx.x * 256 + threadIdx.x;
  if (i < n4) {
    float4 v = ((const float4*)in)[i];
    f16x4v o = {(f16)v.x, (f16)v.y, (f16)v.z, (f16)v.w};
    ((f16x4v*)out)[i] = o;
  }
}

extern "C" void kernel_launch(void* const* d_in, const int* in_sizes, int n_in,
                              void* d_out, int out_size, void* d_ws, size_t ws_size,
                              hipStream_t stream) {
  (void)in_sizes; (void)n_in; (void)out_size; (void)ws_size;
  const float* x_in  = (const float*)d_in[0];
  const float* emb_w = (const float*)d_in[1];
  const float* emb_b = (const float*)d_in[2];
  const float* cg_w  = (const float*)d_in[3];
  const float* cg_b  = (const float*)d_in[4];
  const float* wq    = (const float*)d_in[5];
  const float* bq    = (const float*)d_in[6];
  const float* wk    = (const float*)d_in[7];
  const float* bk    = (const float*)d_in[8];
  const float* wv    = (const float*)d_in[9];
  const float* bv    = (const float*)d_in[10];
  const float* wo    = (const float*)d_in[11];
  const float* bo    = (const float*)d_in[12];
  const float* fc1w  = (const float*)d_in[13];
  const float* fc1b  = (const float*)d_in[14];
  const float* fc2w  = (const float*)d_in[15];
  const float* fc2b  = (const float*)d_in[16];
  const float* lnw   = (const float*)d_in[17];
  const float* lnb   = (const float*)d_in[18];
  const float* outw  = (const float*)d_in[19];
  const float* outb  = (const float*)d_in[20];
  float* outp = (float*)d_out;

  const size_t M1 = 1024ull * 1024ull;
  char* wsp = (char*)d_ws;
  size_t off = 0;
  auto alloc = [&](size_t bytes) -> void* {
    void* r = wsp + off;
    off += (bytes + 255) & ~(size_t)255;
    return r;
  };

  // fp16 weights
  f16* embw_h = (f16*)alloc(M1 * 2);
  f16* outw_h = (f16*)alloc(M1 * 2);
  f16* cgw_h  = (f16*)alloc(6 * M1 * 2);
  f16* wq_h   = (f16*)alloc(6 * M1 * 2);
  f16* wk_h   = (f16*)alloc(6 * M1 * 2);
  f16* wv_h   = (f16*)alloc(6 * M1 * 2);
  f16* wo_h   = (f16*)alloc(6 * M1 * 2);
  f16* fc1_h  = (f16*)alloc(6 * M1 * 2);
  f16* fc2_h  = (f16*)alloc(6 * M1 * 2);
  // fp16 activations
  f16* xh0   = (f16*)alloc(2 * M1 * 2);
  f16* xh    = (f16*)alloc(2 * M1 * 2);
  f16* xT    = (f16*)alloc(2 * M1 * 2);
  f16* cmb   = (f16*)alloc(2 * M1 * 2);
  f16* x2    = (f16*)alloc(2 * M1 * 2);
  f16* qb    = (f16*)alloc(2 * M1 * 2);
  f16* kbuf  = (f16*)alloc(2 * M1 * 2);
  f16* vT    = (f16*)alloc(2 * M1 * 2);
  f16* attnb = (f16*)alloc(2 * M1 * 2);
  f16* xf    = (f16*)alloc(2 * M1 * 2);
  f16* h1    = (f16*)alloc(2 * M1 * 2);
  // fp32 buffers
  float* resid = (float*)alloc(2 * M1 * 4);
  float* pre   = (float*)alloc(2 * M1 * 4);

  auto cvt = [&](const float* src, f16* dst, size_t n) {
    cvt_f32_f16<<<dim3((unsigned)(n / 1024)), 256, 0, stream>>>(src, dst, (long long)(n / 4));
  };
  cvt(x_in, xh0, 2 * M1);
  cvt(emb_w, embw_h, M1);
  cvt(outw, outw_h, M1);
  cvt(cg_w, cgw_h, 6 * M1);
  cvt(wq, wq_h, 6 * M1);
  cvt(wk, wk_h, 6 * M1);
  cvt(wv, wv_h, 6 * M1);
  cvt(wo, wo_h, 6 * M1);
  cvt(fc1w, fc1_h, 6 * M1);
  cvt(fc2w, fc2_h, 6 * M1);

  // embedding: xh = x @ emb_w^T + emb_b
  gemm_nt<EPI_F16B><<<dim3(16, 32, 1), 256, 0, stream>>>(
      GP{xh0, embw_h, nullptr, nullptr, emb_b, nullptr, nullptr,
         xh, nullptr, nullptr, nullptr, 1024, 1024, 1024, 1024, 0, 0, 0});

  for (int i = 0; i < 6; ++i) {
    const f16* cgwi = cgw_h + (size_t)i * M1;
    const f16* wqi = wq_h + (size_t)i * M1;
    const f16* wki = wk_h + (size_t)i * M1;
    const f16* wvi = wv_h + (size_t)i * M1;
    const f16* woi = wo_h + (size_t)i * M1;
    const f16* f1i = fc1_h + (size_t)i * M1;
    const f16* f2i = fc2_h + (size_t)i * M1;

    transpose_k<<<dim3(16, 16, 2), 256, 0, stream>>>(xh, xT);

    // cm = sigmoid(xh @ cg_w^T + cg_b)
    gemm_nt<EPI_SIG><<<dim3(16, 32, 1), 256, 0, stream>>>(
        GP{xh, cgwi, nullptr, nullptr, cg_b + i * 1024, nullptr, nullptr,
           cmb, nullptr, nullptr, nullptr, 1024, 1024, 1024, 1024, 0, 0, 0});

    // x2[b] = cm[b] @ x[b]  (NT against xT)
    gemm_nt<EPI_F16><<<dim3(16, 16, 2), 256, 0, stream>>>(
        GP{cmb, xT, nullptr, nullptr, nullptr, nullptr, nullptr,
           x2, nullptr, nullptr, nullptr, 1024, 1024, 1024, 1024,
           (long long)M1, (long long)M1, (long long)M1});

    // fused q/k/v projection: q,k -> [B,H,L,DK]; v -> [B,H,DK,L]
    gemm_nt<EPI_QKV3><<<dim3(48, 32, 1), 256, 0, stream>>>(
        GP{x2, wqi, wki, wvi, bq + i * 1024, bk + i * 1024, bv + i * 1024,
           qb, kbuf, vT, nullptr, 1024, 1024, 1024, 0, 0, 0, 0});

    // fused attention
    fattn<<<dim3(16, 32), 256, 0, stream>>>(qb, kbuf, vT, attnb);

    // x = attn @ wo^T + bo  -> resid (fp32) + xf (fp16)
    gemm_nt<EPI_RESID><<<dim3(16, 32, 1), 256, 0, stream>>>(
        GP{attnb, woi, nullptr, nullptr, bo + i * 1024, nullptr, nullptr,
           resid, xf, nullptr, nullptr, 1024, 1024, 1024, 0, 0, 0, 0});
    gemm_nt<EPI_RELU><<<dim3(16, 32, 1), 256, 0, stream>>>(
        GP{xf, f1i, nullptr, nullptr, fc1b + i * 1024, nullptr, nullptr,
           h1, nullptr, nullptr, nullptr, 1024, 1024, 1024, 1024, 0, 0, 0});
    gemm_nt<EPI_FC2><<<dim3(16, 32, 1), 256, 0, stream>>>(
        GP{h1, f2i, nullptr, nullptr, fc2b + i * 1024, nullptr, nullptr,
           pre, nullptr, nullptr, resid, 1024, 1024, 1024, 0, 0, 0, 0});
    ln_k<<<dim3(2048), 256, 0, stream>>>(pre, lnw + i * 1024, lnb + i * 1024, xh);
  }

  gemm_nt<EPI_OUT><<<dim3(16, 32, 1), 256, 0, stream>>>(
      GP{xh, outw_h, nullptr, nullptr, outb, nullptr, nullptr,
         outp, nullptr, nullptr, nullptr, 1024, 1024, 1024, 0, 0, 0, 0});
}

// Round 4
// 832.631 us; speedup vs baseline: 2.0395x; 1.1501x over previous
//
#include <hip/hip_runtime.h>

// CausaFormer forward on MI355X. fp16 MFMA GEMMs w/ fp32 accumulate.
// B=2, L=1024, D=1024, NL=6, H=16, DK=64.
// R4: counted-vmcnt 4-buffer pipelines (GEMM + fattn), transposed-softmax
//     fattn (swapped QK^T, packed P writes, defer-max).

typedef _Float16 f16;
typedef _Float16 f16x8 __attribute__((ext_vector_type(8)));
typedef _Float16 f16x4v __attribute__((ext_vector_type(4)));
typedef float f32x4 __attribute__((ext_vector_type(4)));

__device__ __forceinline__ void gload16(const void* g, void* l) {
  __builtin_amdgcn_global_load_lds((const __attribute__((address_space(1))) void*)g,
                                   (__attribute__((address_space(3))) void*)l, 16, 0, 0);
}

// Epilogue modes
enum {
  EPI_F16 = 0,   // f16 store, no bias           (cm@x)
  EPI_F16B,      // f16 store + bias             (embedding)
  EPI_SIG,       // sigmoid(v+bias) -> f16       (causal-graph gate)
  EPI_RELU,      // relu(v+bias) -> f16          (fc1)
  EPI_QKV3,      // fused q/k/v: q,k -> [B,H,L,DK]; v -> [B,H,DK,L]
  EPI_RESID,     // v+bias -> f32 C and f16 C2   (wo: residual + fc1 input)
  EPI_FC2,       // v+bias+resid -> f32          (fc2: pre-LN sum)
  EPI_OUT        // v+bias -> f32                (final projection)
};

struct GP {
  const f16* A; const f16* W; const f16* W2; const f16* W3;
  const float* bias; const float* bias2; const float* bias3;
  void* C; void* C2; void* C3; const float* resid;
  int lda; int ldw; int ldc;
  long long sA; long long sW; long long sC;
};

// NT GEMM: C[m][n] = epi( sum_k A[m][k] * W[n][k] ), K=1024 fixed (16 steps).
// 64x64 tile, BK=64, 4 waves 2x2 (wave tile 32x32). 4-buffer LDS,
// stage-ahead-2 with counted vmcnt (8 outstanding = 2 future tiles),
// one raw barrier per K-step. XOR-swizzled chunks (conflict-free, measured).
template<int EPI>
__global__ __launch_bounds__(256, 2) void gemm_nt(GP p) {
  __shared__ __align__(16) f16 As[4][64 * 64];
  __shared__ __align__(16) f16 Bs[4][64 * 64];

  const int tid = threadIdx.x;
  const int lane = tid & 63;
  const int wid = tid >> 6;
  const int wr = wid >> 1;
  const int wc = wid & 1;
  const int z = blockIdx.z;
  const int m0 = blockIdx.y * 64;
  const int n0 = blockIdx.x * 64;

  const f16* Ab = p.A + (long long)z * p.sA;
  const f16* Wb;
  int n0l = n0, nm = 0;
  if constexpr (EPI == EPI_QKV3) {
    nm = n0 >> 10;
    Wb = (nm == 0 ? p.W : nm == 1 ? p.W2 : p.W3);
    n0l = n0 & 1023;
  } else {
    Wb = p.W + (long long)z * p.sW;
  }

  auto stage = [&](int buf, int t) {  // 4 gload16 per thread
    const int ko = t * 64;
#pragma unroll
    for (int u = 0; u < 2; ++u) {
      const int c = u * 4 + wid;
      const int s = c * 64 + lane;
      const int row = s >> 3, ch = s & 7;          // 8 x 16B chunks per 128B row
      const int sk = ((ch ^ (row & 7)) << 3);      // pre-swizzled source k-offset
      gload16(Ab + (long long)(m0 + row) * p.lda + ko + sk, &As[buf][c * 512]);
      gload16(Wb + (long long)(n0l + row) * p.ldw + ko + sk, &Bs[buf][c * 512]);
    }
  };

  stage(0, 0);
  stage(1, 1);

  f32x4 acc[2][2] = {};
  const int lr = lane & 15;
  const int lg = lane >> 4;

  for (int t = 0; t < 16; ++t) {
    if (t + 2 < 16) stage((t + 2) & 3, t + 2);
    if (t + 2 < 16)      asm volatile("s_waitcnt vmcnt(8)" ::: "memory");
    else if (t + 1 < 16) asm volatile("s_waitcnt vmcnt(4)" ::: "memory");
    else                 asm volatile("s_waitcnt vmcnt(0)" ::: "memory");
    __builtin_amdgcn_s_barrier();
    const int cur = t & 3;
#pragma unroll
    for (int ks = 0; ks < 2; ++ks) {
      f16x8 fa[2], fb[2];
#pragma unroll
      for (int i = 0; i < 2; ++i) {
        const int r = wr * 32 + i * 16 + lr;
        fa[i] = *(const f16x8*)((const char*)&As[cur][0] + r * 128 +
                                (((ks * 4 + lg) ^ (r & 7)) << 4));
      }
#pragma unroll
      for (int j = 0; j < 2; ++j) {
        const int r = wc * 32 + j * 16 + lr;
        fb[j] = *(const f16x8*)((const char*)&Bs[cur][0] + r * 128 +
                                (((ks * 4 + lg) ^ (r & 7)) << 4));
      }
#pragma unroll
      for (int i = 0; i < 2; ++i)
#pragma unroll
        for (int j = 0; j < 2; ++j)
          acc[i][j] = __builtin_amdgcn_mfma_f32_16x16x32_f16(fa[i], fb[j], acc[i][j], 0, 0, 0);
    }
    // all LDS reads complete before any wave passes the next barrier
    asm volatile("s_waitcnt lgkmcnt(0)" ::: "memory");
  }

  // ---- epilogue: D[row=(lane>>4)*4+r][col=lane&15] per frag ----
  const int rq = lg * 4;
  const float* bp = p.bias;
  if constexpr (EPI == EPI_QKV3)
    bp = nm == 0 ? p.bias : nm == 1 ? p.bias2 : p.bias3;
#pragma unroll
  for (int i = 0; i < 2; ++i) {
#pragma unroll
    for (int j = 0; j < 2; ++j) {
      const int colb = n0l + wc * 32 + j * 16 + lr;
      float bv = 0.f;
      if constexpr (EPI != EPI_F16) bv = bp ? bp[colb] : 0.f;
#pragma unroll
      for (int r = 0; r < 4; ++r) {
        const int row = m0 + wr * 32 + i * 16 + rq + r;
        float v = acc[i][j][r] + bv;
        if constexpr (EPI == EPI_SIG)  v = 1.f / (1.f + __expf(-v));
        if constexpr (EPI == EPI_RELU) v = fmaxf(v, 0.f);
        if constexpr (EPI == EPI_F16 || EPI == EPI_F16B || EPI == EPI_SIG || EPI == EPI_RELU) {
          ((f16*)p.C)[(long long)z * p.sC + (long long)row * p.ldc + colb] = (f16)v;
        } else if constexpr (EPI == EPI_QKV3) {
          const int b = row >> 10, l = row & 1023;
          const int h = colb >> 6, dk = colb & 63;
          if (nm == 2)
            ((f16*)p.C3)[((((long long)b * 16 + h) * 64 + dk) << 10) + l] = (f16)v;
          else
            ((f16*)(nm == 0 ? p.C : p.C2))[((((long long)b * 16 + h) * 1024 + l) << 6) + dk] = (f16)v;
        } else if constexpr (EPI == EPI_RESID) {
          const long long idx = (long long)row * 1024 + colb;
          ((float*)p.C)[idx] = v;
          ((f16*)p.C2)[idx] = (f16)v;
        } else if constexpr (EPI == EPI_FC2) {
          const long long idx = (long long)row * 1024 + colb;
          ((float*)p.C)[idx] = v + p.resid[idx];
        } else if constexpr (EPI == EPI_OUT) {
          ((float*)p.C)[(long long)row * 1024 + colb] = v;
        }
      }
    }
  }
}

// Fused flash attention, transposed-softmax form. Grid (L/64, B*H), 4 waves.
// Wave w owns Q rows [w*16, w*16+16). S^T = mfma(K,Q): thread holds 16 j's of
// ONE row i=lane&15 -> scalar m/l state, 2-shuffle row max, packed b64 P
// writes. PV: O^T = mfma(V^T, P^T). 4-buffer K/V, counted vmcnt.
__global__ __launch_bounds__(256, 2) void fattn(const f16* __restrict__ q,
                                                const f16* __restrict__ kk,
                                                const f16* __restrict__ vt,
                                                f16* __restrict__ out) {
  __shared__ __align__(16) f16 Ks[4][64 * 64];   // [j][dk] rows 128B, swizzled
  __shared__ __align__(16) f16 Vs[4][64 * 64];   // [dk][j] rows 128B, swizzled
  __shared__ __align__(16) f16 Ps[4][16 * 64];   // Q staging, then per-wave P^T

  const int tid = threadIdx.x;
  const int lane = tid & 63;
  const int wid = tid >> 6;
  const int lr = lane & 15;
  const int lg = lane >> 4;
  const int bh = blockIdx.y;
  const int b = bh >> 4, h = bh & 15;
  const int q0 = blockIdx.x * 64;

  const f16* qp = q + (long long)bh * 65536;
  const f16* kp = kk + (long long)bh * 65536;
  const f16* vp = vt + (long long)bh * 65536;
  char* pbase = (char*)&Ps[0][0];

  // ---- stage Q tile (64x64) into Ps via LDS (keeps loop free of
  //      register-producing vm loads), read Q fragments, then reuse Ps for P.
#pragma unroll
  for (int u = 0; u < 2; ++u) {
    const int c = u * 4 + wid;
    const int s = c * 64 + lane;
    const int row = s >> 3, ch = s & 7;
    gload16(qp + (long long)(q0 + row) * 64 + ((ch ^ (row & 7)) << 3),
            pbase + c * 1024);
  }
  asm volatile("s_waitcnt vmcnt(0)" ::: "memory");
  __syncthreads();
  f16x8 qf[2];
#pragma unroll
  for (int ks = 0; ks < 2; ++ks) {
    const int row = wid * 16 + lr;
    qf[ks] = *(const f16x8*)(pbase + row * 128 + (((ks * 4 + lg) ^ (lr & 7)) << 4));
  }
  asm volatile("s_waitcnt lgkmcnt(0)" ::: "memory");
  __syncthreads();

  f32x4 o[4] = {};     // O^T: col=i (=lr), rows d = df*16 + lg*4 + r
  f32x4 ol = {};       // row-sum via ones-MFMA (all rows equal)
  float m_r = -1e30f;  // running raw max for row i

  const f16x8 ones = {(f16)1.f, (f16)1.f, (f16)1.f, (f16)1.f,
                      (f16)1.f, (f16)1.f, (f16)1.f, (f16)1.f};

  auto stage = [&](int buf, int t) {  // 4 gload16 per thread
    const int j0 = t * 64;
#pragma unroll
    for (int u = 0; u < 2; ++u) {
      const int c = u * 4 + wid;
      const int s = c * 64 + lane;
      const int row = s >> 3, ch = s & 7;
      const int sch = (ch ^ (row & 7)) * 8;
      gload16(kp + (long long)(j0 + row) * 64 + sch, &Ks[buf][c * 512]);
      gload16(vp + (long long)row * 1024 + j0 + sch, &Vs[buf][c * 512]);
    }
  };

  stage(0, 0);
  stage(1, 1);

  constexpr float SCL = 0.125f * 1.44269504089f;  // 1/sqrt(64) * log2(e)
  for (int t = 0; t < 16; ++t) {
    if (t + 2 < 16) stage((t + 2) & 3, t + 2);
    if (t + 2 < 16)      asm volatile("s_waitcnt vmcnt(8)" ::: "memory");
    else if (t + 1 < 16) asm volatile("s_waitcnt vmcnt(4)" ::: "memory");
    else                 asm volatile("s_waitcnt vmcnt(0)" ::: "memory");
    __builtin_amdgcn_s_barrier();
    const int cur = t & 3;

    // ---- S^T = K . Q : D[row=j][col=i] ----
    f32x4 s[4] = {};
#pragma unroll
    for (int ks = 0; ks < 2; ++ks) {
      f16x8 fk[4];
#pragma unroll
      for (int jf = 0; jf < 4; ++jf) {
        const int j = jf * 16 + lr;
        fk[jf] = *(const f16x8*)((const char*)&Ks[cur][0] + j * 128 +
                                 (((ks * 4 + lg) ^ (j & 7)) << 4));
      }
#pragma unroll
      for (int jf = 0; jf < 4; ++jf)
        s[jf] = __builtin_amdgcn_mfma_f32_16x16x32_f16(fk[jf], qf[ks], s[jf], 0, 0, 0);
    }

    // ---- online softmax: all 16 values belong to row i = lr ----
    float pm = s[0][0];
#pragma unroll
    for (int jf = 0; jf < 4; ++jf)
#pragma unroll
      for (int r = 0; r < 4; ++r) pm = fmaxf(pm, s[jf][r]);
    pm = fmaxf(pm, __shfl_xor(pm, 16));
    pm = fmaxf(pm, __shfl_xor(pm, 32));
    if (__any(pm > m_r)) {  // defer-max: skip rescale when no growth (exact)
      const float mn = fmaxf(m_r, pm);
      const float sf = __builtin_exp2f((m_r - mn) * SCL);
      m_r = mn;
#pragma unroll
      for (int df = 0; df < 4; ++df)
#pragma unroll
        for (int r = 0; r < 4; ++r) o[df][r] *= sf;
#pragma unroll
      for (int r = 0; r < 4; ++r) ol[r] *= sf;
    }
    const float msc = m_r * SCL;
    float pv[4][4];
#pragma unroll
    for (int jf = 0; jf < 4; ++jf)
#pragma unroll
      for (int r = 0; r < 4; ++r)
        pv[jf][r] = __builtin_exp2f(__builtin_fmaf(s[jf][r], SCL, -msc));
    // column-0 intervention: halve P[j=0] (j = jf*16+lg*4+r = 0).
    if (t == 0 && lg == 0) pv[0][0] *= 0.5f;

    // ---- P^T -> LDS, packed 4x b64 (4 consecutive j at fixed i=lr) ----
#pragma unroll
    for (int jf = 0; jf < 4; ++jf) {
      f16x4v pk = {(f16)pv[jf][0], (f16)pv[jf][1], (f16)pv[jf][2], (f16)pv[jf][3]};
      const int j0 = jf * 16 + lg * 4;
      *(f16x4v*)(pbase + wid * 2048 + lr * 128 +
                 (((j0 >> 3) ^ (lr & 7)) << 4) + (j0 & 7) * 2) = pk;
    }
    asm volatile("s_waitcnt lgkmcnt(0)" ::: "memory");
    __builtin_amdgcn_sched_barrier(0);

    // ---- O^T += V^T . P^T (+ ones row-sum) ----
#pragma unroll
    for (int ks = 0; ks < 2; ++ks) {
      f16x8 fp, fv[4];
      fp = *(const f16x8*)(pbase + wid * 2048 + lr * 128 +
                           (((ks * 4 + lg) ^ (lr & 7)) << 4));
#pragma unroll
      for (int df = 0; df < 4; ++df) {
        const int d = df * 16 + lr;
        fv[df] = *(const f16x8*)((const char*)&Vs[cur][0] + d * 128 +
                                 (((ks * 4 + lg) ^ (d & 7)) << 4));
      }
#pragma unroll
      for (int df = 0; df < 4; ++df)
        o[df] = __builtin_amdgcn_mfma_f32_16x16x32_f16(fv[df], fp, o[df], 0, 0, 0);
      ol = __builtin_amdgcn_mfma_f32_16x16x32_f16(ones, fp, ol, 0, 0, 0);
    }
    // denominator correction: ones-MFMA summed the halved p0; add it again.
    if (t == 0) {
      const float hv = __shfl(pv[0][0], lane & 15);
#pragma unroll
      for (int r = 0; r < 4; ++r) ol[r] += hv;
    }
    asm volatile("s_waitcnt lgkmcnt(0)" ::: "memory");
  }

  // ---- normalize + scatter O^T to [B,L,D] ----
  const float inv = 1.f / ol[0];
  const long long rowi = q0 + wid * 16 + lr;
#pragma unroll
  for (int df = 0; df < 4; ++df) {
    f16x4v ov = {(f16)(o[df][0] * inv), (f16)(o[df][1] * inv),
                 (f16)(o[df][2] * inv), (f16)(o[df][3] * inv)};
    *(f16x4v*)(out + (long long)b * 1048576 + rowi * 1024 + h * 64 +
               df * 16 + lg * 4) = ov;
  }
}

// LayerNorm over D=1024, fp32 in, f16 out.
__global__ __launch_bounds__(256) void ln_k(const float* __restrict__ pre,
                                            const float* __restrict__ w,
                                            const float* __restrict__ b,
                                            f16* __restrict__ out) {
  const long long row = blockIdx.x;
  const int t = threadIdx.x;
  const float* x = pre + row * 1024;
  float4 v = *(const float4*)(x + t * 4);
  float s = v.x + v.y + v.z + v.w;
  float s2 = v.x * v.x + v.y * v.y + v.z * v.z + v.w * v.w;
#pragma unroll
  for (int o = 1; o < 64; o <<= 1) { s += __shfl_xor(s, o); s2 += __shfl_xor(s2, o); }
  __shared__ float rs[4], rs2[4];
  if ((t & 63) == 0) { rs[t >> 6] = s; rs2[t >> 6] = s2; }
  __syncthreads();
  s = rs[0] + rs[1] + rs[2] + rs[3];
  s2 = rs2[0] + rs2[1] + rs2[2] + rs2[3];
  const float mean = s * (1.f / 1024.f);
  const float var = s2 * (1.f / 1024.f) - mean * mean;
  const float inv = rsqrtf(var + 1e-5f);
  f16x4v o4;
#pragma unroll
  for (int c = 0; c < 4; ++c) {
    const float xv = (&v.x)[c];
    o4[c] = (f16)((xv - mean) * inv * w[t * 4 + c] + b[t * 4 + c]);
  }
  *(f16x4v*)(out + row * 1024 + t * 4) = o4;
}

// f16 [B,L,D] -> [B,D,L] transpose via 64x64 LDS tile.
__global__ __launch_bounds__(256) void transpose_k(const f16* __restrict__ x,
                                                   f16* __restrict__ xt) {
  __shared__ f16 tile[64][65];
  const int c0 = blockIdx.x * 64;
  const int l0 = blockIdx.y * 64;
  const long long zb = (long long)blockIdx.z * (1024 * 1024);
  const int t = threadIdx.x;
#pragma unroll
  for (int it = 0; it < 16; ++it) {
    const int idx = it * 256 + t;
    const int r = idx >> 6, c = idx & 63;
    tile[r][c] = x[zb + (long long)(l0 + r) * 1024 + c0 + c];
  }
  __syncthreads();
#pragma unroll
  for (int it = 0; it < 16; ++it) {
    const int idx = it * 256 + t;
    const int r = idx >> 6, c = idx & 63;
    xt[zb + (long long)(c0 + r) * 1024 + l0 + c] = tile[c][r];
  }
}

__global__ __launch_bounds__(256) void cvt_f32_f16(const float* __restrict__ in,
                                                   f16* __restrict__ out, long long n4) {
  const long long i = (long long)blockIdx.x * 256 + threadIdx.x;
  if (i < n4) {
    float4 v = ((const float4*)in)[i];
    f16x4v o = {(f16)v.x, (f16)v.y, (f16)v.z, (f16)v.w};
    ((f16x4v*)out)[i] = o;
  }
}

extern "C" void kernel_launch(void* const* d_in, const int* in_sizes, int n_in,
                              void* d_out, int out_size, void* d_ws, size_t ws_size,
                              hipStream_t stream) {
  (void)in_sizes; (void)n_in; (void)out_size; (void)ws_size;
  const float* x_in  = (const float*)d_in[0];
  const float* emb_w = (const float*)d_in[1];
  const float* emb_b = (const float*)d_in[2];
  const float* cg_w  = (const float*)d_in[3];
  const float* cg_b  = (const float*)d_in[4];
  const float* wq    = (const float*)d_in[5];
  const float* bq    = (const float*)d_in[6];
  const float* wk    = (const float*)d_in[7];
  const float* bk    = (const float*)d_in[8];
  const float* wv    = (const float*)d_in[9];
  const float* bv    = (const float*)d_in[10];
  const float* wo    = (const float*)d_in[11];
  const float* bo    = (const float*)d_in[12];
  const float* fc1w  = (const float*)d_in[13];
  const float* fc1b  = (const float*)d_in[14];
  const float* fc2w  = (const float*)d_in[15];
  const float* fc2b  = (const float*)d_in[16];
  const float* lnw   = (const float*)d_in[17];
  const float* lnb   = (const float*)d_in[18];
  const float* outw  = (const float*)d_in[19];
  const float* outb  = (const float*)d_in[20];
  float* outp = (float*)d_out;

  const size_t M1 = 1024ull * 1024ull;
  char* wsp = (char*)d_ws;
  size_t off = 0;
  auto alloc = [&](size_t bytes) -> void* {
    void* r = wsp + off;
    off += (bytes + 255) & ~(size_t)255;
    return r;
  };

  // fp16 weights
  f16* embw_h = (f16*)alloc(M1 * 2);
  f16* outw_h = (f16*)alloc(M1 * 2);
  f16* cgw_h  = (f16*)alloc(6 * M1 * 2);
  f16* wq_h   = (f16*)alloc(6 * M1 * 2);
  f16* wk_h   = (f16*)alloc(6 * M1 * 2);
  f16* wv_h   = (f16*)alloc(6 * M1 * 2);
  f16* wo_h   = (f16*)alloc(6 * M1 * 2);
  f16* fc1_h  = (f16*)alloc(6 * M1 * 2);
  f16* fc2_h  = (f16*)alloc(6 * M1 * 2);
  // fp16 activations
  f16* xh0   = (f16*)alloc(2 * M1 * 2);
  f16* xh    = (f16*)alloc(2 * M1 * 2);
  f16* xT    = (f16*)alloc(2 * M1 * 2);
  f16* cmb   = (f16*)alloc(2 * M1 * 2);
  f16* x2    = (f16*)alloc(2 * M1 * 2);
  f16* qb    = (f16*)alloc(2 * M1 * 2);
  f16* kbuf  = (f16*)alloc(2 * M1 * 2);
  f16* vT    = (f16*)alloc(2 * M1 * 2);
  f16* attnb = (f16*)alloc(2 * M1 * 2);
  f16* xf    = (f16*)alloc(2 * M1 * 2);
  f16* h1    = (f16*)alloc(2 * M1 * 2);
  // fp32 buffers
  float* resid = (float*)alloc(2 * M1 * 4);
  float* pre   = (float*)alloc(2 * M1 * 4);

  auto cvt = [&](const float* src, f16* dst, size_t n) {
    cvt_f32_f16<<<dim3((unsigned)(n / 1024)), 256, 0, stream>>>(src, dst, (long long)(n / 4));
  };
  cvt(x_in, xh0, 2 * M1);
  cvt(emb_w, embw_h, M1);
  cvt(outw, outw_h, M1);
  cvt(cg_w, cgw_h, 6 * M1);
  cvt(wq, wq_h, 6 * M1);
  cvt(wk, wk_h, 6 * M1);
  cvt(wv, wv_h, 6 * M1);
  cvt(wo, wo_h, 6 * M1);
  cvt(fc1w, fc1_h, 6 * M1);
  cvt(fc2w, fc2_h, 6 * M1);

  // embedding: xh = x @ emb_w^T + emb_b
  gemm_nt<EPI_F16B><<<dim3(16, 32, 1), 256, 0, stream>>>(
      GP{xh0, embw_h, nullptr, nullptr, emb_b, nullptr, nullptr,
         xh, nullptr, nullptr, nullptr, 1024, 1024, 1024, 0, 0, 0});

  for (int i = 0; i < 6; ++i) {
    const f16* cgwi = cgw_h + (size_t)i * M1;
    const f16* wqi = wq_h + (size_t)i * M1;
    const f16* wki = wk_h + (size_t)i * M1;
    const f16* wvi = wv_h + (size_t)i * M1;
    const f16* woi = wo_h + (size_t)i * M1;
    const f16* f1i = fc1_h + (size_t)i * M1;
    const f16* f2i = fc2_h + (size_t)i * M1;

    transpose_k<<<dim3(16, 16, 2), 256, 0, stream>>>(xh, xT);

    // cm = sigmoid(xh @ cg_w^T + cg_b)
    gemm_nt<EPI_SIG><<<dim3(16, 32, 1), 256, 0, stream>>>(
        GP{xh, cgwi, nullptr, nullptr, cg_b + i * 1024, nullptr, nullptr,
           cmb, nullptr, nullptr, nullptr, 1024, 1024, 1024, 0, 0, 0});

    // x2[b] = cm[b] @ x[b]  (NT against xT)
    gemm_nt<EPI_F16><<<dim3(16, 16, 2), 256, 0, stream>>>(
        GP{cmb, xT, nullptr, nullptr, nullptr, nullptr, nullptr,
           x2, nullptr, nullptr, nullptr, 1024, 1024, 1024,
           (long long)M1, (long long)M1, (long long)M1});

    // fused q/k/v projection: q,k -> [B,H,L,DK]; v -> [B,H,DK,L]
    gemm_nt<EPI_QKV3><<<dim3(48, 32, 1), 256, 0, stream>>>(
        GP{x2, wqi, wki, wvi, bq + i * 1024, bk + i * 1024, bv + i * 1024,
           qb, kbuf, vT, nullptr, 1024, 1024, 0, 0, 0, 0});

    // fused attention
    fattn<<<dim3(16, 32), 256, 0, stream>>>(qb, kbuf, vT, attnb);

    // x = attn @ wo^T + bo  -> resid (fp32) + xf (fp16)
    gemm_nt<EPI_RESID><<<dim3(16, 32, 1), 256, 0, stream>>>(
        GP{attnb, woi, nullptr, nullptr, bo + i * 1024, nullptr, nullptr,
           resid, xf, nullptr, nullptr, 1024, 1024, 0, 0, 0, 0});
    gemm_nt<EPI_RELU><<<dim3(16, 32, 1), 256, 0, stream>>>(
        GP{xf, f1i, nullptr, nullptr, fc1b + i * 1024, nullptr, nullptr,
           h1, nullptr, nullptr, nullptr, 1024, 1024, 1024, 0, 0, 0});
    gemm_nt<EPI_FC2><<<dim3(16, 32, 1), 256, 0, stream>>>(
        GP{h1, f2i, nullptr, nullptr, fc2b + i * 1024, nullptr, nullptr,
           pre, nullptr, nullptr, resid, 1024, 1024, 0, 0, 0, 0});
    ln_k<<<dim3(2048), 256, 0, stream>>>(pre, lnw + i * 1024, lnb + i * 1024, xh);
  }

  gemm_nt<EPI_OUT><<<dim3(16, 32, 1), 256, 0, stream>>>(
      GP{xh, outw_h, nullptr, nullptr, outb, nullptr, nullptr,
         outp, nullptr, nullptr, nullptr, 1024, 1024, 0, 0, 0, 0});
}